// Round 16
// baseline (188.001 us; speedup 1.0000x reference)
//
#include <hip/hip_runtime.h>
#include <hip/hip_bf16.h>
#include <math.h>

#define TT 2048
#define HH 2048
#define EE 8
#define II 1408
#define PMAX 4608    // 4096 slots + 8*63 worst-case 64-padding
#define MAXTILES 48  // >= sum ceil(padded_e/128) worst case (44); mult of 8
#define G1TILES (MAXTILES * (II / 64))   // 1056 gemm1 block slots
#define G2TILES (MAXTILES * (HH / 64))   // 1536 gemm2 block slots
#define NCONV 5632                        // blocks per weight conversion
#define ESPLIT 4                          // expert-group pipeline split

typedef short bf16x8 __attribute__((ext_vector_type(8)));
typedef float f32x4 __attribute__((ext_vector_type(4)));
typedef unsigned int u32;
typedef unsigned short u16;

__device__ __forceinline__ u16 f2bf(float f) {
  union { float f; u32 u; } v; v.f = f;
  u32 r = v.u + 0x7fffu + ((v.u >> 16) & 1u);
  return (u16)(r >> 16);
}

__device__ __forceinline__ float bf2f(u16 b) {
  union { u32 u; float f; } v; v.u = ((u32)b) << 16; return v.f;
}

__device__ __forceinline__ void gload16(const void* g, void* l) {
  __builtin_amdgcn_global_load_lds((const __attribute__((address_space(1))) u32*)g,
                                   (__attribute__((address_space(3))) u32*)l, 16, 0, 0);
}

// ---- conv block body: w[e][K][N] fp32 -> wb[e][N][K] bf16, one 64x64 tile ----
// LDS tile padded to 76 u16/row (38 dwords, stride%32=6 -> 2-way max = free).
__device__ __forceinline__ void conv_block(const float* __restrict__ w, u16* __restrict__ wb,
                                           int K, int N, int b, u16* smem) {
  int nx = N / 64, ky = K / 64;
  int n0 = (b % nx) * 64;
  int k0 = ((b / nx) % ky) * 64;
  int e  = b / (nx * ky);
  u16 (*sT)[76] = (u16(*)[76])smem;
  const float* we = w + (size_t)e * K * N;
  u16* wbe = wb + (size_t)e * K * N;
  int tid = threadIdx.x;
  int kl = tid >> 4, n4 = tid & 15;
#pragma unroll
  for (int j = 0; j < 4; ++j) {
    int k = kl + j * 16;
    float4 v = *(const float4*)(we + (size_t)(k0 + k) * N + n0 + n4 * 4);
    sT[n4 * 4 + 0][k] = f2bf(v.x);
    sT[n4 * 4 + 1][k] = f2bf(v.y);
    sT[n4 * 4 + 2][k] = f2bf(v.z);
    sT[n4 * 4 + 3][k] = f2bf(v.w);
  }
  __syncthreads();
  int nl = tid >> 3, kc = tid & 7;
#pragma unroll
  for (int j = 0; j < 2; ++j) {
    int n = nl + j * 32;
    uint4 v = *(const uint4*)(&sT[n][kc * 8]);
    *(uint4*)(wbe + (size_t)(n0 + n) * K + k0 + kc * 8) = v;
  }
}

// ---- grouped GEMM body, 128x64x64, single-buffer (proven loop), XCD-pinned decode ----
// MODE 0: silu -> outp (midB, II row stride). MODE 2: outp = y bf16 (HH row stride).
// Processes only tiles with expert in [ELO, EHI).
template <int KDIM, int MODE, int ELO, int EHI>
__device__ __forceinline__ void gemm128_body(int L, const u16* __restrict__ A,
                                             const u16* __restrict__ B,
                                             const int* __restrict__ t_row0,
                                             const int* __restrict__ t_e,
                                             const int* __restrict__ t_rlim,
                                             u16* __restrict__ outp, u16* smem) {
  constexpr int Ndim = (MODE == 2) ? HH : II;
  constexpr int NCB = Ndim / 64;
  constexpr int NT = KDIM / 64;

  int xcd = L & 7;
  int q = L >> 3;
  int g = q / NCB;
  int n0b = q - g * NCB;
  int ti = g * 8 + xcd;
  int row0 = t_row0[ti];
  if (row0 < 0) return;
  int e = t_e[ti];
  if (e < ELO || e >= EHI) return;
  int rlim = t_rlim[ti];
  int n0 = n0b * 64;

  u16 (*sA)[64] = (u16(*)[64])smem;            // [128][64]
  u16 (*sB)[64] = (u16(*)[64])(smem + 8192);   // [64][64]

  int tid = threadIdx.x;
  int lane = tid & 63, wv = tid >> 6;
  int wm = wv >> 1, wn = wv & 1;
  int fr = lane & 15, kg = lane >> 4;

  int rA = lane >> 3;
  int colsw = ((lane & 7) ^ rA) * 8;
  const u16* Abase = A + (size_t)(row0 + rA) * KDIM + colsw;
  const u16* Bbase = B + (size_t)e * (size_t)Ndim * KDIM + (size_t)(n0 + rA) * KDIM + colsw;

  f32x4 acc[4][2];
#pragma unroll
  for (int m = 0; m < 4; ++m)
#pragma unroll
    for (int n = 0; n < 2; ++n)
      acc[m][n] = (f32x4){0.f, 0.f, 0.f, 0.f};

  for (int t = 0; t < NT; ++t) {
    int kof = t * 64;
#pragma unroll
    for (int j = 0; j < 4; ++j) {
      int c = wv * 4 + j;
      gload16(Abase + (size_t)c * 8 * KDIM + kof, &sA[c * 8][0]);
    }
#pragma unroll
    for (int j = 0; j < 2; ++j) {
      int c = wv * 2 + j;
      gload16(Bbase + (size_t)c * 8 * KDIM + kof, &sB[c * 8][0]);
    }
    __syncthreads();
#pragma unroll
    for (int kh = 0; kh < 2; ++kh) {
      bf16x8 af[4], bg[2];
      int cbyte = (kh * 64 + kg * 16) ^ ((fr & 7) << 4);
#pragma unroll
      for (int m = 0; m < 4; ++m)
        af[m] = *(const bf16x8*)((const char*)&sA[0][0] + (wm * 64 + m * 16 + fr) * 128 + cbyte);
#pragma unroll
      for (int n = 0; n < 2; ++n)
        bg[n] = *(const bf16x8*)((const char*)&sB[0][0] + (wn * 32 + n * 16 + fr) * 128 + cbyte);
#pragma unroll
      for (int m = 0; m < 4; ++m)
#pragma unroll
        for (int n = 0; n < 2; ++n)
          acc[m][n] = __builtin_amdgcn_mfma_f32_16x16x32_bf16(af[m], bg[n], acc[m][n], 0, 0, 0);
    }
    __syncthreads();
  }

#pragma unroll
  for (int m = 0; m < 4; ++m) {
    int lr = wm * 64 + m * 16 + kg * 4;
#pragma unroll
    for (int n = 0; n < 2; ++n) {
      int lc = wn * 32 + n * 16 + fr;
#pragma unroll
      for (int r = 0; r < 4; ++r) {
        int rr = row0 + lr + r;
        if (rr < rlim) {
          if constexpr (MODE == 0) {
            float v = acc[m][n][r];
            float s = v / (1.f + expf(-v));
            outp[(size_t)rr * II + n0 + lc] = f2bf(s);
          } else {
            outp[(size_t)rr * HH + n0 + lc] = f2bf(acc[m][n][r]);
          }
        }
      }
    }
  }
}

// ---------------- K1: router (4 waves/block) || conv1 (w1: K=HH, N=II) ----------------
__global__ void router_conv_kernel(const float* __restrict__ x, const float* __restrict__ gw,
                                   int* __restrict__ tk_id, float* __restrict__ tk_w,
                                   const float* __restrict__ w1, u16* __restrict__ w1b) {
  __shared__ u16 smem[64 * 76];
  if (blockIdx.x < TT / 4) {
    int wv = threadIdx.x >> 6, lane = threadIdx.x & 63;
    int t = blockIdx.x * 4 + wv;
    float acc[EE];
#pragma unroll
    for (int e = 0; e < EE; ++e) acc[e] = 0.f;
    const float* xr = x + (size_t)t * HH;
    for (int h = lane; h < HH; h += 64) {
      float xv = xr[h];
      const float* g = gw + (size_t)h * EE;
#pragma unroll
      for (int e = 0; e < EE; ++e) acc[e] += xv * g[e];
    }
#pragma unroll
    for (int off = 32; off > 0; off >>= 1) {
#pragma unroll
      for (int e = 0; e < EE; ++e) acc[e] += __shfl_down(acc[e], off, 64);
    }
    if (lane == 0) {
      int i0 = 0;
#pragma unroll
      for (int e = 1; e < EE; ++e) if (acc[e] > acc[i0]) i0 = e;
      int i1 = (i0 == 0) ? 1 : 0;
#pragma unroll
      for (int e = 0; e < EE; ++e) { if (e == i0) continue; if (acc[e] > acc[i1]) i1 = e; }
      float d = acc[i1] - acc[i0];
      float p1 = expf(d);
      float w0 = 1.f / (1.f + p1);
      float w1v = p1 * w0;
      tk_id[2 * t] = i0; tk_id[2 * t + 1] = i1;
      tk_w[2 * t] = w0;  tk_w[2 * t + 1] = w1v;
    }
  } else {
    conv_block(w1, w1b, HH, II, blockIdx.x - TT / 4, smem);
  }
}

// ---------------- K2: count + scan (64-padded) + assign + 128-tile table ----------------
__global__ void scanassign_kernel(const int* __restrict__ tk_id, const float* __restrict__ tk_w,
                                  int* __restrict__ offsets, int* __restrict__ poff,
                                  int* __restrict__ tok_list, float* __restrict__ wt_list,
                                  int* __restrict__ islot,
                                  int* __restrict__ t_row0, int* __restrict__ t_e,
                                  int* __restrict__ t_rlim) {
  __shared__ int s_cnt[EE];
  __shared__ int s_off[EE + 1];
  __shared__ int s_poff[EE + 1];
  __shared__ int s_cur[EE];
  int tid = threadIdx.x;
  if (tid < EE) { s_cnt[tid] = 0; s_cur[tid] = 0; }
  __syncthreads();
  for (int i = tid; i < 2 * TT; i += 256) atomicAdd(&s_cnt[tk_id[i]], 1);
  __syncthreads();
  if (tid == 0) {
    int s = 0, ps = 0;
    for (int e = 0; e < EE; ++e) {
      s_off[e] = s; s_poff[e] = ps;
      s += s_cnt[e];
      ps += ((s_cnt[e] + 63) >> 6) << 6;
    }
    s_off[EE] = s; s_poff[EE] = ps;
    for (int e = 0; e <= EE; ++e) { offsets[e] = s_off[e]; poff[e] = s_poff[e]; }
    int nt = 0;
    for (int e = 0; e < EE; ++e) {
      for (int r0 = s_poff[e]; r0 < s_poff[e + 1]; r0 += 128) {
        t_row0[nt] = r0; t_e[nt] = e; t_rlim[nt] = s_poff[e + 1]; ++nt;
      }
    }
    for (int i = nt; i < MAXTILES; ++i) t_row0[i] = -1;
  }
  __syncthreads();
  for (int t = tid; t < TT; t += 256) {
#pragma unroll
    for (int k = 0; k < 2; ++k) {
      int e = tk_id[2 * t + k];
      int p = atomicAdd(&s_cur[e], 1);
      tok_list[s_off[e] + p] = t;
      wt_list[s_off[e] + p] = tk_w[2 * t + k];
      islot[2 * t + k] = s_poff[e] + p;
    }
  }
}

// ---------------- K3: gather x -> bf16 xg[padded slot][H] ----------------
__global__ void gather_x_kernel(const float* __restrict__ x, const int* __restrict__ tok_list,
                                const int* __restrict__ offsets, const int* __restrict__ poff,
                                u16* __restrict__ xg) {
  int p = blockIdx.x;
  if (p >= poff[EE]) return;
  int e = 0;
#pragma unroll
  for (int q = 1; q < EE; ++q) if (p >= poff[q]) e = q;
  int cnt = offsets[e + 1] - offsets[e];
  int r = p - poff[e]; if (r >= cnt) r = cnt - 1;
  int tok = tok_list[offsets[e] + r];
  int c = threadIdx.x * 8;
  float4 v0 = *(const float4*)(x + (size_t)tok * HH + c);
  float4 v1 = *(const float4*)(x + (size_t)tok * HH + c + 4);
  u16 o[8] = { f2bf(v0.x), f2bf(v0.y), f2bf(v0.z), f2bf(v0.w),
               f2bf(v1.x), f2bf(v1.y), f2bf(v1.z), f2bf(v1.w) };
  *(uint4*)(xg + (size_t)p * HH + c) = *(uint4*)o;
}

// ---------------- K4a: gemm1 (experts 0..ESPLIT-1) || conv2 ----------------
__global__ void k4a_kernel(const u16* __restrict__ xg, const u16* __restrict__ w1b,
                           const int* __restrict__ t_row0, const int* __restrict__ t_e,
                           const int* __restrict__ t_rlim, u16* __restrict__ midB,
                           const float* __restrict__ w2, u16* __restrict__ w2b) {
  __shared__ u16 smem[12288];
  if (blockIdx.x >= G1TILES) {
    conv_block(w2, w2b, II, HH, blockIdx.x - G1TILES, smem);
    return;
  }
  gemm128_body<HH, 0, 0, ESPLIT>(blockIdx.x, xg, w1b, t_row0, t_e, t_rlim, midB, smem);
}

// ---------------- K4b: gemm1 (experts ESPLIT..7) || gemm2 (experts 0..ESPLIT-1) ----------
__global__ void k4b_kernel(const u16* __restrict__ xg, const u16* __restrict__ w1b,
                           u16* __restrict__ midB, const u16* __restrict__ w2b,
                           u16* __restrict__ y,
                           const int* __restrict__ t_row0, const int* __restrict__ t_e,
                           const int* __restrict__ t_rlim) {
  __shared__ u16 smem[12288];
  if (blockIdx.x < G1TILES) {
    gemm128_body<HH, 0, ESPLIT, EE>(blockIdx.x, xg, w1b, t_row0, t_e, t_rlim, midB, smem);
  } else {
    gemm128_body<II, 2, 0, ESPLIT>(blockIdx.x - G1TILES, midB, w2b, t_row0, t_e, t_rlim, y, smem);
  }
}

// ---------------- K5: gemm2 (experts ESPLIT..7) ----------------
__global__ void k5_kernel(const u16* __restrict__ midB, const u16* __restrict__ w2b,
                          u16* __restrict__ y,
                          const int* __restrict__ t_row0, const int* __restrict__ t_e,
                          const int* __restrict__ t_rlim) {
  __shared__ u16 smem[12288];
  gemm128_body<II, 2, ESPLIT, EE>(blockIdx.x, midB, w2b, t_row0, t_e, t_rlim, y, smem);
}

// ---------------- K6: combine: out[t] = w0*y[s0] + w1*y[s1]  (y bf16) ----------------
__global__ void combine_kernel(const u16* __restrict__ y, const int* __restrict__ islot,
                               const float* __restrict__ tk_w, float* __restrict__ out) {
  int t = blockIdx.x;
  int h = threadIdx.x * 8;
  int s0 = islot[2 * t], s1 = islot[2 * t + 1];
  float w0 = tk_w[2 * t], w1 = tk_w[2 * t + 1];
  uint4 a = *(const uint4*)(y + (size_t)s0 * HH + h);
  uint4 b = *(const uint4*)(y + (size_t)s1 * HH + h);
  const u16* ap = (const u16*)&a;
  const u16* bp = (const u16*)&b;
  float* op = out + (size_t)t * HH + h;
  float4 r0, r1;
  r0.x = w0 * bf2f(ap[0]) + w1 * bf2f(bp[0]);
  r0.y = w0 * bf2f(ap[1]) + w1 * bf2f(bp[1]);
  r0.z = w0 * bf2f(ap[2]) + w1 * bf2f(bp[2]);
  r0.w = w0 * bf2f(ap[3]) + w1 * bf2f(bp[3]);
  r1.x = w0 * bf2f(ap[4]) + w1 * bf2f(bp[4]);
  r1.y = w0 * bf2f(ap[5]) + w1 * bf2f(bp[5]);
  r1.z = w0 * bf2f(ap[6]) + w1 * bf2f(bp[6]);
  r1.w = w0 * bf2f(ap[7]) + w1 * bf2f(bp[7]);
  *(float4*)(op) = r0;
  *(float4*)(op + 4) = r1;
}

// ================= fallback path (proven; used only if ws too small) ===========
__global__ void zero_kernel(float4* __restrict__ out4, int n4) {
  int i = blockIdx.x * blockDim.x + threadIdx.x;
  int stride = gridDim.x * blockDim.x;
  float4 z; z.x = 0.f; z.y = 0.f; z.z = 0.f; z.w = 0.f;
  for (int j = i; j < n4; j += stride) out4[j] = z;
}

__global__ void router_kernel(const float* __restrict__ x, const float* __restrict__ gw,
                              int* __restrict__ tk_id, float* __restrict__ tk_w) {
  int t = blockIdx.x;
  int lane = threadIdx.x;
  float acc[EE];
#pragma unroll
  for (int e = 0; e < EE; ++e) acc[e] = 0.f;
  const float* xr = x + (size_t)t * HH;
  for (int h = lane; h < HH; h += 64) {
    float xv = xr[h];
    const float* g = gw + (size_t)h * EE;
#pragma unroll
    for (int e = 0; e < EE; ++e) acc[e] += xv * g[e];
  }
#pragma unroll
  for (int off = 32; off > 0; off >>= 1) {
#pragma unroll
    for (int e = 0; e < EE; ++e) acc[e] += __shfl_down(acc[e], off, 64);
  }
  if (lane == 0) {
    int i0 = 0;
#pragma unroll
    for (int e = 1; e < EE; ++e) if (acc[e] > acc[i0]) i0 = e;
    int i1 = (i0 == 0) ? 1 : 0;
#pragma unroll
    for (int e = 0; e < EE; ++e) { if (e == i0) continue; if (acc[e] > acc[i1]) i1 = e; }
    float d = acc[i1] - acc[i0];
    float p1 = expf(d);
    float w0 = 1.f / (1.f + p1);
    float w1v = p1 * w0;
    tk_id[2 * t] = i0; tk_id[2 * t + 1] = i1;
    tk_w[2 * t] = w0;  tk_w[2 * t + 1] = w1v;
  }
}

__launch_bounds__(256, 2)
__global__ void gemm1_small(const float* __restrict__ x, const float* __restrict__ w1,
                            const int* __restrict__ tok_list, const int* __restrict__ offsets,
                            u16* __restrict__ mid) {
  int e = blockIdx.z;
  int g_off = offsets[e];
  int n_e = offsets[e + 1] - g_off;
  int row0 = blockIdx.y * 64;
  if (row0 >= n_e) return;
  int n0 = blockIdx.x * 64;
  __shared__ u16 sA[64][72];
  __shared__ u16 sB[64][72];
  __shared__ int s_tok[64];
  int tid = threadIdx.x;
  if (tid < 64) {
    int r = row0 + tid;
    s_tok[tid] = tok_list[g_off + ((r < n_e) ? r : (n_e - 1))];
  }
  __syncthreads();
  int lane = tid & 63;
  int wv = tid >> 6;
  int wm = wv >> 1, wn = wv & 1;
  int fr = lane & 15, kg = lane >> 4;
  f32x4 acc[2][2];
#pragma unroll
  for (int i = 0; i < 2; ++i)
#pragma unroll
    for (int j = 0; j < 2; ++j) acc[i][j] = (f32x4){0.f, 0.f, 0.f, 0.f};
  const float* w1e = w1 + (size_t)e * HH * II;
  for (int k0 = 0; k0 < HH; k0 += 64) {
#pragma unroll
    for (int i = 0; i < 4; ++i) {
      int idx = tid + i * 256;
      int r = idx >> 4, c4 = idx & 15;
      float4 v = *(const float4*)(x + (size_t)s_tok[r] * HH + k0 + c4 * 4);
      unsigned long long pk = (unsigned long long)f2bf(v.x)
                            | ((unsigned long long)f2bf(v.y) << 16)
                            | ((unsigned long long)f2bf(v.z) << 32)
                            | ((unsigned long long)f2bf(v.w) << 48);
      *(unsigned long long*)(&sA[r][c4 * 4]) = pk;
    }
#pragma unroll
    for (int i = 0; i < 4; ++i) {
      int idx = tid + i * 256;
      int kk = idx >> 4, c4 = idx & 15;
      float4 v = *(const float4*)(w1e + (size_t)(k0 + kk) * II + n0 + c4 * 4);
      sB[c4 * 4 + 0][kk] = f2bf(v.x);
      sB[c4 * 4 + 1][kk] = f2bf(v.y);
      sB[c4 * 4 + 2][kk] = f2bf(v.z);
      sB[c4 * 4 + 3][kk] = f2bf(v.w);
    }
    __syncthreads();
#pragma unroll
    for (int kk = 0; kk < 64; kk += 32) {
      bf16x8 af[2], bg[2];
#pragma unroll
      for (int m = 0; m < 2; ++m) af[m] = *(const bf16x8*)(&sA[wm * 32 + m * 16 + fr][kk + kg * 8]);
#pragma unroll
      for (int n = 0; n < 2; ++n) bg[n] = *(const bf16x8*)(&sB[wn * 32 + n * 16 + fr][kk + kg * 8]);
#pragma unroll
      for (int m = 0; m < 2; ++m)
#pragma unroll
        for (int n = 0; n < 2; ++n)
          acc[m][n] = __builtin_amdgcn_mfma_f32_16x16x32_bf16(af[m], bg[n], acc[m][n], 0, 0, 0);
    }
    __syncthreads();
  }
#pragma unroll
  for (int m = 0; m < 2; ++m)
#pragma unroll
    for (int n = 0; n < 2; ++n)
#pragma unroll
      for (int r = 0; r < 4; ++r) {
        int lr = wm * 32 + m * 16 + kg * 4 + r;
        int lc = wn * 32 + n * 16 + fr;
        if (row0 + lr < n_e) {
          float v = acc[m][n][r];
          float s = v / (1.f + expf(-v));
          mid[(size_t)(g_off + row0 + lr) * II + n0 + lc] = f2bf(s);
        }
      }
}

__launch_bounds__(256, 2)
__global__ void gemm2_small(const u16* __restrict__ mid, const float* __restrict__ w2,
                            const int* __restrict__ tok_list, const float* __restrict__ wt_list,
                            const int* __restrict__ offsets, float* __restrict__ out) {
  int e = blockIdx.z;
  int g_off = offsets[e];
  int n_e = offsets[e + 1] - g_off;
  int row0 = blockIdx.y * 64;
  if (row0 >= n_e) return;
  int n0 = blockIdx.x * 64;
  __shared__ u16 sA[64][72];
  __shared__ u16 sB[64][72];
  __shared__ int s_tok[64];
  __shared__ float s_wt[64];
  int tid = threadIdx.x;
  if (tid < 64) {
    int r = row0 + tid;
    int cr = (r < n_e) ? r : (n_e - 1);
    s_tok[tid] = tok_list[g_off + cr];
    s_wt[tid] = wt_list[g_off + cr];
  }
  __syncthreads();
  int lane = tid & 63;
  int wv = tid >> 6;
  int wm = wv >> 1, wn = wv & 1;
  int fr = lane & 15, kg = lane >> 4;
  f32x4 acc[2][2];
#pragma unroll
  for (int i = 0; i < 2; ++i)
#pragma unroll
    for (int j = 0; j < 2; ++j) acc[i][j] = (f32x4){0.f, 0.f, 0.f, 0.f};
  const float* w2e = w2 + (size_t)e * II * HH;
  for (int k0 = 0; k0 < II; k0 += 64) {
#pragma unroll
    for (int i = 0; i < 2; ++i) {
      int idx = tid + i * 256;
      int r = idx >> 3, c8 = idx & 7;
      int gr = row0 + r; if (gr >= n_e) gr = n_e - 1;
      uint4 v = *(const uint4*)(mid + (size_t)(g_off + gr) * II + k0 + c8 * 8);
      *(uint4*)(&sA[r][c8 * 8]) = v;
    }
#pragma unroll
    for (int i = 0; i < 4; ++i) {
      int idx = tid + i * 256;
      int kk = idx >> 4, c4 = idx & 15;
      float4 v = *(const float4*)(w2e + (size_t)(k0 + kk) * HH + n0 + c4 * 4);
      sB[c4 * 4 + 0][kk] = f2bf(v.x);
      sB[c4 * 4 + 1][kk] = f2bf(v.y);
      sB[c4 * 4 + 2][kk] = f2bf(v.z);
      sB[c4 * 4 + 3][kk] = f2bf(v.w);
    }
    __syncthreads();
#pragma unroll
    for (int kk = 0; kk < 64; kk += 32) {
      bf16x8 af[2], bg[2];
#pragma unroll
      for (int m = 0; m < 2; ++m) af[m] = *(const bf16x8*)(&sA[wm * 32 + m * 16 + fr][kk + kg * 8]);
#pragma unroll
      for (int n = 0; n < 2; ++n) bg[n] = *(const bf16x8*)(&sB[wn * 32 + n * 16 + fr][kk + kg * 8]);
#pragma unroll
      for (int m = 0; m < 2; ++m)
#pragma unroll
        for (int n = 0; n < 2; ++n)
          acc[m][n] = __builtin_amdgcn_mfma_f32_16x16x32_bf16(af[m], bg[n], acc[m][n], 0, 0, 0);
    }
    __syncthreads();
  }
#pragma unroll
  for (int m = 0; m < 2; ++m)
#pragma unroll
    for (int n = 0; n < 2; ++n)
#pragma unroll
      for (int r = 0; r < 4; ++r) {
        int lr = wm * 32 + m * 16 + kg * 4 + r;
        int lc = wn * 32 + n * 16 + fr;
        if (row0 + lr < n_e) {
          float v = acc[m][n][r] * s_wt[lr];
          atomicAdd(out + (size_t)s_tok[lr] * HH + n0 + lc, v);
        }
      }
}

extern "C" void kernel_launch(void* const* d_in, const int* in_sizes, int n_in,
                              void* d_out, int out_size, void* d_ws, size_t ws_size,
                              hipStream_t stream) {
  const float* x  = (const float*)d_in[0];
  const float* gw = (const float*)d_in[1];
  const float* w1 = (const float*)d_in[2];
  const float* w2 = (const float*)d_in[3];
  float* out = (float*)d_out;

  char* ws = (char*)d_ws;
  int*   tk_id    = (int*)(ws);
  float* tk_w     = (float*)(ws + 16384);
  int*   offsets  = (int*)(ws + 32832);
  int*   poff     = (int*)(ws + 32896);
  int*   tok_list = (int*)(ws + 33024);
  float* wt_list  = (float*)(ws + 49408);
  int*   islot    = (int*)(ws + 65792);
  int*   t_row0   = (int*)(ws + 98304);
  int*   t_e      = (int*)(ws + 98560);
  int*   t_rlim   = (int*)(ws + 98816);

  u16* xg    = (u16*)(ws + (1u << 20));   // [PMAX][2048] bf16 = 18.9 MB
  u16* midBp = (u16*)(ws + (20u << 20));  // [PMAX][1408] bf16 = 13.0 MB
  u16* w1b   = (u16*)(ws + (33u << 20));  // [8][1408][2048] bf16 (N-major); dead after gemm1
  u16* w2b   = (u16*)(ws + 80740352u);    // [8][2048][1408] bf16 (N-major)
  u16* y     = (u16*)(ws + (33u << 20));  // [PMAX][2048] bf16, ALIASES w1b
  const size_t NEED = 126877696u;

  if (ws_size >= NEED) {
    // K1: router (512 blocks x 4 waves) || conv1 (5632 blocks)
    router_conv_kernel<<<TT / 4 + NCONV, 256, 0, stream>>>(x, gw, tk_id, tk_w, w1, w1b);
    // K2: scan/assign/tile-table (1 block)
    scanassign_kernel<<<1, 256, 0, stream>>>(tk_id, tk_w, offsets, poff, tok_list, wt_list,
                                             islot, t_row0, t_e, t_rlim);
    // K3: gather x -> bf16 padded slots
    gather_x_kernel<<<PMAX, 256, 0, stream>>>(x, tok_list, offsets, poff, xg);
    // K4a: gemm1 experts [0,4) || conv2
    k4a_kernel<<<G1TILES + NCONV, 256, 0, stream>>>(
        xg, w1b, t_row0, t_e, t_rlim, midBp, w2, w2b);
    // K4b: gemm1 experts [4,8) || gemm2 experts [0,4)   (midB/w2b coherent across launch)
    k4b_kernel<<<G1TILES + G2TILES, 256, 0, stream>>>(
        xg, w1b, midBp, w2b, y, t_row0, t_e, t_rlim);
    // K5: gemm2 experts [4,8)
    k5_kernel<<<G2TILES, 256, 0, stream>>>(midBp, w2b, y, t_row0, t_e, t_rlim);
    // K6: combine
    combine_kernel<<<TT, 256, 0, stream>>>(y, islot, tk_w, out);
  } else {
    u16* mid0 = (u16*)(ws + 131072);
    router_kernel<<<TT, 64, 0, stream>>>(x, gw, tk_id, tk_w);
    scanassign_kernel<<<1, 256, 0, stream>>>(tk_id, tk_w, offsets, poff, tok_list, wt_list,
                                             islot, t_row0, t_e, t_rlim);
    zero_kernel<<<1024, 256, 0, stream>>>((float4*)out, TT * HH / 4);
    gemm1_small<<<dim3(II / 64, TT / 64, EE), 256, 0, stream>>>(x, w1, tok_list, offsets, mid0);
    gemm2_small<<<dim3(HH / 64, TT / 64, EE), 256, 0, stream>>>(mid0, w2, tok_list, wt_list, offsets, out);
  }
}

// Round 17
// 172.895 us; speedup vs baseline: 1.0874x; 1.0874x over previous
//
#include <hip/hip_runtime.h>
#include <hip/hip_bf16.h>
#include <math.h>

#define TT 2048
#define HH 2048
#define EE 8
#define II 1408
#define PMAX 4608    // 4096 slots + 8*63 worst-case 64-padding
#define MAXTILES 48  // >= sum ceil(padded_e/128) worst case (44); mult of 8
#define G1TILES (MAXTILES * (II / 64))   // 1056 gemm1 block slots
#define NCONV 5632                        // blocks per weight conversion

typedef short bf16x8 __attribute__((ext_vector_type(8)));
typedef float f32x4 __attribute__((ext_vector_type(4)));
typedef unsigned int u32;
typedef unsigned short u16;

__device__ __forceinline__ u16 f2bf(float f) {
  union { float f; u32 u; } v; v.f = f;
  u32 r = v.u + 0x7fffu + ((v.u >> 16) & 1u);
  return (u16)(r >> 16);
}

__device__ __forceinline__ float bf2f(u16 b) {
  union { u32 u; float f; } v; v.u = ((u32)b) << 16; return v.f;
}

__device__ __forceinline__ void gload16(const void* g, void* l) {
  __builtin_amdgcn_global_load_lds((const __attribute__((address_space(1))) u32*)g,
                                   (__attribute__((address_space(3))) u32*)l, 16, 0, 0);
}

// ---- conv block body: w[e][K][N] fp32 -> wb[e][N][K] bf16, one 64x64 tile ----
// LDS tile padded to 76 u16/row (38 dwords, odd-ish stride -> <=2-way conflicts).
__device__ __forceinline__ void conv_block(const float* __restrict__ w, u16* __restrict__ wb,
                                           int K, int N, int b, u16* smem) {
  int nx = N / 64, ky = K / 64;
  int n0 = (b % nx) * 64;
  int k0 = ((b / nx) % ky) * 64;
  int e  = b / (nx * ky);
  u16 (*sT)[76] = (u16(*)[76])smem;
  const float* we = w + (size_t)e * K * N;
  u16* wbe = wb + (size_t)e * K * N;
  int tid = threadIdx.x;
  int kl = tid >> 4, n4 = tid & 15;
#pragma unroll
  for (int j = 0; j < 4; ++j) {
    int k = kl + j * 16;
    float4 v = *(const float4*)(we + (size_t)(k0 + k) * N + n0 + n4 * 4);
    sT[n4 * 4 + 0][k] = f2bf(v.x);
    sT[n4 * 4 + 1][k] = f2bf(v.y);
    sT[n4 * 4 + 2][k] = f2bf(v.z);
    sT[n4 * 4 + 3][k] = f2bf(v.w);
  }
  __syncthreads();
  int nl = tid >> 3, kc = tid & 7;
#pragma unroll
  for (int j = 0; j < 2; ++j) {
    int n = nl + j * 32;
    uint4 v = *(const uint4*)(&sT[n][kc * 8]);
    *(uint4*)(wbe + (size_t)(n0 + n) * K + k0 + kc * 8) = v;
  }
}

// ---- grouped GEMM body, 128x64x64, single-buffer (proven loop), XCD-pinned decode ----
// MODE 0: silu -> outp (midB, II row stride). MODE 2: outp = y bf16 (HH row stride).
template <int KDIM, int MODE>
__device__ __forceinline__ void gemm128_body(int L, const u16* __restrict__ A,
                                             const u16* __restrict__ B,
                                             const int* __restrict__ t_row0,
                                             const int* __restrict__ t_e,
                                             const int* __restrict__ t_rlim,
                                             u16* __restrict__ outp, u16* smem) {
  constexpr int Ndim = (MODE == 2) ? HH : II;
  constexpr int NCB = Ndim / 64;
  constexpr int NT = KDIM / 64;

  int xcd = L & 7;
  int q = L >> 3;
  int g = q / NCB;
  int n0b = q - g * NCB;
  int ti = g * 8 + xcd;
  int row0 = t_row0[ti];
  if (row0 < 0) return;
  int e = t_e[ti];
  int rlim = t_rlim[ti];
  int n0 = n0b * 64;

  u16 (*sA)[64] = (u16(*)[64])smem;            // [128][64]
  u16 (*sB)[64] = (u16(*)[64])(smem + 8192);   // [64][64]

  int tid = threadIdx.x;
  int lane = tid & 63, wv = tid >> 6;
  int wm = wv >> 1, wn = wv & 1;
  int fr = lane & 15, kg = lane >> 4;

  int rA = lane >> 3;
  int colsw = ((lane & 7) ^ rA) * 8;
  const u16* Abase = A + (size_t)(row0 + rA) * KDIM + colsw;
  const u16* Bbase = B + (size_t)e * (size_t)Ndim * KDIM + (size_t)(n0 + rA) * KDIM + colsw;

  f32x4 acc[4][2];
#pragma unroll
  for (int m = 0; m < 4; ++m)
#pragma unroll
    for (int n = 0; n < 2; ++n)
      acc[m][n] = (f32x4){0.f, 0.f, 0.f, 0.f};

  for (int t = 0; t < NT; ++t) {
    int kof = t * 64;
#pragma unroll
    for (int j = 0; j < 4; ++j) {
      int c = wv * 4 + j;
      gload16(Abase + (size_t)c * 8 * KDIM + kof, &sA[c * 8][0]);
    }
#pragma unroll
    for (int j = 0; j < 2; ++j) {
      int c = wv * 2 + j;
      gload16(Bbase + (size_t)c * 8 * KDIM + kof, &sB[c * 8][0]);
    }
    __syncthreads();
#pragma unroll
    for (int kh = 0; kh < 2; ++kh) {
      bf16x8 af[4], bg[2];
      int cbyte = (kh * 64 + kg * 16) ^ ((fr & 7) << 4);
#pragma unroll
      for (int m = 0; m < 4; ++m)
        af[m] = *(const bf16x8*)((const char*)&sA[0][0] + (wm * 64 + m * 16 + fr) * 128 + cbyte);
#pragma unroll
      for (int n = 0; n < 2; ++n)
        bg[n] = *(const bf16x8*)((const char*)&sB[0][0] + (wn * 32 + n * 16 + fr) * 128 + cbyte);
#pragma unroll
      for (int m = 0; m < 4; ++m)
#pragma unroll
        for (int n = 0; n < 2; ++n)
          acc[m][n] = __builtin_amdgcn_mfma_f32_16x16x32_bf16(af[m], bg[n], acc[m][n], 0, 0, 0);
    }
    __syncthreads();
  }

#pragma unroll
  for (int m = 0; m < 4; ++m) {
    int lr = wm * 64 + m * 16 + kg * 4;
#pragma unroll
    for (int n = 0; n < 2; ++n) {
      int lc = wn * 32 + n * 16 + fr;
#pragma unroll
      for (int r = 0; r < 4; ++r) {
        int rr = row0 + lr + r;
        if (rr < rlim) {
          if constexpr (MODE == 0) {
            float v = acc[m][n][r];
            float s = v / (1.f + expf(-v));
            outp[(size_t)rr * II + n0 + lc] = f2bf(s);
          } else {
            outp[(size_t)rr * HH + n0 + lc] = f2bf(acc[m][n][r]);
          }
        }
      }
    }
  }
}

// ---------------- K1: router (4 waves/block) || conv1 (w1: K=HH, N=II) ----------------
__global__ void router_conv_kernel(const float* __restrict__ x, const float* __restrict__ gw,
                                   int* __restrict__ tk_id, float* __restrict__ tk_w,
                                   const float* __restrict__ w1, u16* __restrict__ w1b) {
  __shared__ u16 smem[64 * 76];
  if (blockIdx.x < TT / 4) {
    int wv = threadIdx.x >> 6, lane = threadIdx.x & 63;
    int t = blockIdx.x * 4 + wv;
    float acc[EE];
#pragma unroll
    for (int e = 0; e < EE; ++e) acc[e] = 0.f;
    const float* xr = x + (size_t)t * HH;
    for (int h = lane; h < HH; h += 64) {
      float xv = xr[h];
      const float* g = gw + (size_t)h * EE;
#pragma unroll
      for (int e = 0; e < EE; ++e) acc[e] += xv * g[e];
    }
#pragma unroll
    for (int off = 32; off > 0; off >>= 1) {
#pragma unroll
      for (int e = 0; e < EE; ++e) acc[e] += __shfl_down(acc[e], off, 64);
    }
    if (lane == 0) {
      int i0 = 0;
#pragma unroll
      for (int e = 1; e < EE; ++e) if (acc[e] > acc[i0]) i0 = e;
      int i1 = (i0 == 0) ? 1 : 0;
#pragma unroll
      for (int e = 0; e < EE; ++e) { if (e == i0) continue; if (acc[e] > acc[i1]) i1 = e; }
      float d = acc[i1] - acc[i0];
      float p1 = expf(d);
      float w0 = 1.f / (1.f + p1);
      float w1v = p1 * w0;
      tk_id[2 * t] = i0; tk_id[2 * t + 1] = i1;
      tk_w[2 * t] = w0;  tk_w[2 * t + 1] = w1v;
    }
  } else {
    conv_block(w1, w1b, HH, II, blockIdx.x - TT / 4, smem);
  }
}

// ---------------- K2: count + scan (64-padded) + assign + 128-tile table ----------------
__global__ void scanassign_kernel(const int* __restrict__ tk_id, const float* __restrict__ tk_w,
                                  int* __restrict__ offsets, int* __restrict__ poff,
                                  int* __restrict__ tok_list, float* __restrict__ wt_list,
                                  int* __restrict__ islot,
                                  int* __restrict__ t_row0, int* __restrict__ t_e,
                                  int* __restrict__ t_rlim) {
  __shared__ int s_cnt[EE];
  __shared__ int s_off[EE + 1];
  __shared__ int s_poff[EE + 1];
  __shared__ int s_cur[EE];
  int tid = threadIdx.x;
  if (tid < EE) { s_cnt[tid] = 0; s_cur[tid] = 0; }
  __syncthreads();
  for (int i = tid; i < 2 * TT; i += 256) atomicAdd(&s_cnt[tk_id[i]], 1);
  __syncthreads();
  if (tid == 0) {
    int s = 0, ps = 0;
    for (int e = 0; e < EE; ++e) {
      s_off[e] = s; s_poff[e] = ps;
      s += s_cnt[e];
      ps += ((s_cnt[e] + 63) >> 6) << 6;
    }
    s_off[EE] = s; s_poff[EE] = ps;
    for (int e = 0; e <= EE; ++e) { offsets[e] = s_off[e]; poff[e] = s_poff[e]; }
    int nt = 0;
    for (int e = 0; e < EE; ++e) {
      for (int r0 = s_poff[e]; r0 < s_poff[e + 1]; r0 += 128) {
        t_row0[nt] = r0; t_e[nt] = e; t_rlim[nt] = s_poff[e + 1]; ++nt;
      }
    }
    for (int i = nt; i < MAXTILES; ++i) t_row0[i] = -1;
  }
  __syncthreads();
  for (int t = tid; t < TT; t += 256) {
#pragma unroll
    for (int k = 0; k < 2; ++k) {
      int e = tk_id[2 * t + k];
      int p = atomicAdd(&s_cur[e], 1);
      tok_list[s_off[e] + p] = t;
      wt_list[s_off[e] + p] = tk_w[2 * t + k];
      islot[2 * t + k] = s_poff[e] + p;
    }
  }
}

// ---------------- K3: gather x -> bf16 xg[padded slot][H] ----------------
__global__ void gather_x_kernel(const float* __restrict__ x, const int* __restrict__ tok_list,
                                const int* __restrict__ offsets, const int* __restrict__ poff,
                                u16* __restrict__ xg) {
  int p = blockIdx.x;
  if (p >= poff[EE]) return;
  int e = 0;
#pragma unroll
  for (int q = 1; q < EE; ++q) if (p >= poff[q]) e = q;
  int cnt = offsets[e + 1] - offsets[e];
  int r = p - poff[e]; if (r >= cnt) r = cnt - 1;
  int tok = tok_list[offsets[e] + r];
  int c = threadIdx.x * 8;
  float4 v0 = *(const float4*)(x + (size_t)tok * HH + c);
  float4 v1 = *(const float4*)(x + (size_t)tok * HH + c + 4);
  u16 o[8] = { f2bf(v0.x), f2bf(v0.y), f2bf(v0.z), f2bf(v0.w),
               f2bf(v1.x), f2bf(v1.y), f2bf(v1.z), f2bf(v1.w) };
  *(uint4*)(xg + (size_t)p * HH + c) = *(uint4*)o;
}

// ---------------- K4: gemm1 (all experts) || conv2 (w2: K=II, N=HH) ----------------
__global__ void gemm1_conv_kernel(const u16* __restrict__ xg, const u16* __restrict__ w1b,
                                  const int* __restrict__ t_row0, const int* __restrict__ t_e,
                                  const int* __restrict__ t_rlim, u16* __restrict__ midB,
                                  const float* __restrict__ w2, u16* __restrict__ w2b) {
  __shared__ u16 smem[12288];
  if (blockIdx.x >= G1TILES) {
    conv_block(w2, w2b, II, HH, blockIdx.x - G1TILES, smem);
    return;
  }
  gemm128_body<HH, 0>(blockIdx.x, xg, w1b, t_row0, t_e, t_rlim, midB, smem);
}

// ---------------- K5: gemm2 (all experts) ----------------
__global__ void gemm2_kernel(const u16* __restrict__ midB, const u16* __restrict__ w2b,
                             u16* __restrict__ y,
                             const int* __restrict__ t_row0, const int* __restrict__ t_e,
                             const int* __restrict__ t_rlim) {
  __shared__ u16 smem[12288];
  gemm128_body<II, 2>(blockIdx.x, midB, w2b, t_row0, t_e, t_rlim, y, smem);
}

// ---------------- K6: combine: out[t] = w0*y[s0] + w1*y[s1]  (y bf16) ----------------
__global__ void combine_kernel(const u16* __restrict__ y, const int* __restrict__ islot,
                               const float* __restrict__ tk_w, float* __restrict__ out) {
  int t = blockIdx.x;
  int h = threadIdx.x * 8;
  int s0 = islot[2 * t], s1 = islot[2 * t + 1];
  float w0 = tk_w[2 * t], w1 = tk_w[2 * t + 1];
  uint4 a = *(const uint4*)(y + (size_t)s0 * HH + h);
  uint4 b = *(const uint4*)(y + (size_t)s1 * HH + h);
  const u16* ap = (const u16*)&a;
  const u16* bp = (const u16*)&b;
  float* op = out + (size_t)t * HH + h;
  float4 r0, r1;
  r0.x = w0 * bf2f(ap[0]) + w1 * bf2f(bp[0]);
  r0.y = w0 * bf2f(ap[1]) + w1 * bf2f(bp[1]);
  r0.z = w0 * bf2f(ap[2]) + w1 * bf2f(bp[2]);
  r0.w = w0 * bf2f(ap[3]) + w1 * bf2f(bp[3]);
  r1.x = w0 * bf2f(ap[4]) + w1 * bf2f(bp[4]);
  r1.y = w0 * bf2f(ap[5]) + w1 * bf2f(bp[5]);
  r1.z = w0 * bf2f(ap[6]) + w1 * bf2f(bp[6]);
  r1.w = w0 * bf2f(ap[7]) + w1 * bf2f(bp[7]);
  *(float4*)(op) = r0;
  *(float4*)(op + 4) = r1;
}

// ================= fallback path (proven; used only if ws too small) ===========
__global__ void zero_kernel(float4* __restrict__ out4, int n4) {
  int i = blockIdx.x * blockDim.x + threadIdx.x;
  int stride = gridDim.x * blockDim.x;
  float4 z; z.x = 0.f; z.y = 0.f; z.z = 0.f; z.w = 0.f;
  for (int j = i; j < n4; j += stride) out4[j] = z;
}

__global__ void router_kernel(const float* __restrict__ x, const float* __restrict__ gw,
                              int* __restrict__ tk_id, float* __restrict__ tk_w) {
  int t = blockIdx.x;
  int lane = threadIdx.x;
  float acc[EE];
#pragma unroll
  for (int e = 0; e < EE; ++e) acc[e] = 0.f;
  const float* xr = x + (size_t)t * HH;
  for (int h = lane; h < HH; h += 64) {
    float xv = xr[h];
    const float* g = gw + (size_t)h * EE;
#pragma unroll
    for (int e = 0; e < EE; ++e) acc[e] += xv * g[e];
  }
#pragma unroll
  for (int off = 32; off > 0; off >>= 1) {
#pragma unroll
    for (int e = 0; e < EE; ++e) acc[e] += __shfl_down(acc[e], off, 64);
  }
  if (lane == 0) {
    int i0 = 0;
#pragma unroll
    for (int e = 1; e < EE; ++e) if (acc[e] > acc[i0]) i0 = e;
    int i1 = (i0 == 0) ? 1 : 0;
#pragma unroll
    for (int e = 0; e < EE; ++e) { if (e == i0) continue; if (acc[e] > acc[i1]) i1 = e; }
    float d = acc[i1] - acc[i0];
    float p1 = expf(d);
    float w0 = 1.f / (1.f + p1);
    float w1v = p1 * w0;
    tk_id[2 * t] = i0; tk_id[2 * t + 1] = i1;
    tk_w[2 * t] = w0;  tk_w[2 * t + 1] = w1v;
  }
}

__launch_bounds__(256, 2)
__global__ void gemm1_small(const float* __restrict__ x, const float* __restrict__ w1,
                            const int* __restrict__ tok_list, const int* __restrict__ offsets,
                            u16* __restrict__ mid) {
  int e = blockIdx.z;
  int g_off = offsets[e];
  int n_e = offsets[e + 1] - g_off;
  int row0 = blockIdx.y * 64;
  if (row0 >= n_e) return;
  int n0 = blockIdx.x * 64;
  __shared__ u16 sA[64][72];
  __shared__ u16 sB[64][72];
  __shared__ int s_tok[64];
  int tid = threadIdx.x;
  if (tid < 64) {
    int r = row0 + tid;
    s_tok[tid] = tok_list[g_off + ((r < n_e) ? r : (n_e - 1))];
  }
  __syncthreads();
  int lane = tid & 63;
  int wv = tid >> 6;
  int wm = wv >> 1, wn = wv & 1;
  int fr = lane & 15, kg = lane >> 4;
  f32x4 acc[2][2];
#pragma unroll
  for (int i = 0; i < 2; ++i)
#pragma unroll
    for (int j = 0; j < 2; ++j) acc[i][j] = (f32x4){0.f, 0.f, 0.f, 0.f};
  const float* w1e = w1 + (size_t)e * HH * II;
  for (int k0 = 0; k0 < HH; k0 += 64) {
#pragma unroll
    for (int i = 0; i < 4; ++i) {
      int idx = tid + i * 256;
      int r = idx >> 4, c4 = idx & 15;
      float4 v = *(const float4*)(x + (size_t)s_tok[r] * HH + k0 + c4 * 4);
      unsigned long long pk = (unsigned long long)f2bf(v.x)
                            | ((unsigned long long)f2bf(v.y) << 16)
                            | ((unsigned long long)f2bf(v.z) << 32)
                            | ((unsigned long long)f2bf(v.w) << 48);
      *(unsigned long long*)(&sA[r][c4 * 4]) = pk;
    }
#pragma unroll
    for (int i = 0; i < 4; ++i) {
      int idx = tid + i * 256;
      int kk = idx >> 4, c4 = idx & 15;
      float4 v = *(const float4*)(w1e + (size_t)(k0 + kk) * II + n0 + c4 * 4);
      sB[c4 * 4 + 0][kk] = f2bf(v.x);
      sB[c4 * 4 + 1][kk] = f2bf(v.y);
      sB[c4 * 4 + 2][kk] = f2bf(v.z);
      sB[c4 * 4 + 3][kk] = f2bf(v.w);
    }
    __syncthreads();
#pragma unroll
    for (int kk = 0; kk < 64; kk += 32) {
      bf16x8 af[2], bg[2];
#pragma unroll
      for (int m = 0; m < 2; ++m) af[m] = *(const bf16x8*)(&sA[wm * 32 + m * 16 + fr][kk + kg * 8]);
#pragma unroll
      for (int n = 0; n < 2; ++n) bg[n] = *(const bf16x8*)(&sB[wn * 32 + n * 16 + fr][kk + kg * 8]);
#pragma unroll
      for (int m = 0; m < 2; ++m)
#pragma unroll
        for (int n = 0; n < 2; ++n)
          acc[m][n] = __builtin_amdgcn_mfma_f32_16x16x32_bf16(af[m], bg[n], acc[m][n], 0, 0, 0);
    }
    __syncthreads();
  }
#pragma unroll
  for (int m = 0; m < 2; ++m)
#pragma unroll
    for (int n = 0; n < 2; ++n)
#pragma unroll
      for (int r = 0; r < 4; ++r) {
        int lr = wm * 32 + m * 16 + kg * 4 + r;
        int lc = wn * 32 + n * 16 + fr;
        if (row0 + lr < n_e) {
          float v = acc[m][n][r];
          float s = v / (1.f + expf(-v));
          mid[(size_t)(g_off + row0 + lr) * II + n0 + lc] = f2bf(s);
        }
      }
}

__launch_bounds__(256, 2)
__global__ void gemm2_small(const u16* __restrict__ mid, const float* __restrict__ w2,
                            const int* __restrict__ tok_list, const float* __restrict__ wt_list,
                            const int* __restrict__ offsets, float* __restrict__ out) {
  int e = blockIdx.z;
  int g_off = offsets[e];
  int n_e = offsets[e + 1] - g_off;
  int row0 = blockIdx.y * 64;
  if (row0 >= n_e) return;
  int n0 = blockIdx.x * 64;
  __shared__ u16 sA[64][72];
  __shared__ u16 sB[64][72];
  __shared__ int s_tok[64];
  __shared__ float s_wt[64];
  int tid = threadIdx.x;
  if (tid < 64) {
    int r = row0 + tid;
    int cr = (r < n_e) ? r : (n_e - 1);
    s_tok[tid] = tok_list[g_off + cr];
    s_wt[tid] = wt_list[g_off + cr];
  }
  __syncthreads();
  int lane = tid & 63;
  int wv = tid >> 6;
  int wm = wv >> 1, wn = wv & 1;
  int fr = lane & 15, kg = lane >> 4;
  f32x4 acc[2][2];
#pragma unroll
  for (int i = 0; i < 2; ++i)
#pragma unroll
    for (int j = 0; j < 2; ++j) acc[i][j] = (f32x4){0.f, 0.f, 0.f, 0.f};
  const float* w2e = w2 + (size_t)e * II * HH;
  for (int k0 = 0; k0 < II; k0 += 64) {
#pragma unroll
    for (int i = 0; i < 2; ++i) {
      int idx = tid + i * 256;
      int r = idx >> 3, c8 = idx & 7;
      int gr = row0 + r; if (gr >= n_e) gr = n_e - 1;
      uint4 v = *(const uint4*)(mid + (size_t)(g_off + gr) * II + k0 + c8 * 8);
      *(uint4*)(&sA[r][c8 * 8]) = v;
    }
#pragma unroll
    for (int i = 0; i < 4; ++i) {
      int idx = tid + i * 256;
      int kk = idx >> 4, c4 = idx & 15;
      float4 v = *(const float4*)(w2e + (size_t)(k0 + kk) * HH + n0 + c4 * 4);
      sB[c4 * 4 + 0][kk] = f2bf(v.x);
      sB[c4 * 4 + 1][kk] = f2bf(v.y);
      sB[c4 * 4 + 2][kk] = f2bf(v.z);
      sB[c4 * 4 + 3][kk] = f2bf(v.w);
    }
    __syncthreads();
#pragma unroll
    for (int kk = 0; kk < 64; kk += 32) {
      bf16x8 af[2], bg[2];
#pragma unroll
      for (int m = 0; m < 2; ++m) af[m] = *(const bf16x8*)(&sA[wm * 32 + m * 16 + fr][kk + kg * 8]);
#pragma unroll
      for (int n = 0; n < 2; ++n) bg[n] = *(const bf16x8*)(&sB[wn * 32 + n * 16 + fr][kk + kg * 8]);
#pragma unroll
      for (int m = 0; m < 2; ++m)
#pragma unroll
        for (int n = 0; n < 2; ++n)
          acc[m][n] = __builtin_amdgcn_mfma_f32_16x16x32_bf16(af[m], bg[n], acc[m][n], 0, 0, 0);
    }
    __syncthreads();
  }
#pragma unroll
  for (int m = 0; m < 2; ++m)
#pragma unroll
    for (int n = 0; n < 2; ++n)
#pragma unroll
      for (int r = 0; r < 4; ++r) {
        int lr = wm * 32 + m * 16 + kg * 4 + r;
        int lc = wn * 32 + n * 16 + fr;
        if (row0 + lr < n_e) {
          float v = acc[m][n][r] * s_wt[lr];
          atomicAdd(out + (size_t)s_tok[lr] * HH + n0 + lc, v);
        }
      }
}

extern "C" void kernel_launch(void* const* d_in, const int* in_sizes, int n_in,
                              void* d_out, int out_size, void* d_ws, size_t ws_size,
                              hipStream_t stream) {
  const float* x  = (const float*)d_in[0];
  const float* gw = (const float*)d_in[1];
  const float* w1 = (const float*)d_in[2];
  const float* w2 = (const float*)d_in[3];
  float* out = (float*)d_out;

  char* ws = (char*)d_ws;
  int*   tk_id    = (int*)(ws);
  float* tk_w     = (float*)(ws + 16384);
  int*   offsets  = (int*)(ws + 32832);
  int*   poff     = (int*)(ws + 32896);
  int*   tok_list = (int*)(ws + 33024);
  float* wt_list  = (float*)(ws + 49408);
  int*   islot    = (int*)(ws + 65792);
  int*   t_row0   = (int*)(ws + 98304);
  int*   t_e      = (int*)(ws + 98560);
  int*   t_rlim   = (int*)(ws + 98816);

  u16* xg    = (u16*)(ws + (1u << 20));   // [PMAX][2048] bf16 = 18.9 MB
  u16* midBp = (u16*)(ws + (20u << 20));  // [PMAX][1408] bf16 = 13.0 MB
  u16* w1b   = (u16*)(ws + (33u << 20));  // [8][1408][2048] bf16 (N-major); dead after gemm1
  u16* w2b   = (u16*)(ws + 80740352u);    // [8][2048][1408] bf16 (N-major)
  u16* y     = (u16*)(ws + (33u << 20));  // [PMAX][2048] bf16, ALIASES w1b
  const size_t NEED = 126877696u;

  if (ws_size >= NEED) {
    // K1: router (512 blocks x 4 waves) || conv1 (5632 blocks)
    router_conv_kernel<<<TT / 4 + NCONV, 256, 0, stream>>>(x, gw, tk_id, tk_w, w1, w1b);
    // K2: scan/assign/tile-table (1 block)
    scanassign_kernel<<<1, 256, 0, stream>>>(tk_id, tk_w, offsets, poff, tok_list, wt_list,
                                             islot, t_row0, t_e, t_rlim);
    // K3: gather x -> bf16 padded slots
    gather_x_kernel<<<PMAX, 256, 0, stream>>>(x, tok_list, offsets, poff, xg);
    // K4: gemm1 (1056 blocks, silu fused -> midBp) || conv2 (5632 blocks)
    gemm1_conv_kernel<<<G1TILES + NCONV, 256, 0, stream>>>(
        xg, w1b, t_row0, t_e, t_rlim, midBp, w2, w2b);
    // K5: gemm2 -> y bf16 (aliases dead w1b)
    gemm2_kernel<<<MAXTILES * (HH / 64), 256, 0, stream>>>(
        midBp, w2b, y, t_row0, t_e, t_rlim);
    // K6: combine
    combine_kernel<<<TT, 256, 0, stream>>>(y, islot, tk_w, out);
  } else {
    u16* mid0 = (u16*)(ws + 131072);
    router_kernel<<<TT, 64, 0, stream>>>(x, gw, tk_id, tk_w);
    scanassign_kernel<<<1, 256, 0, stream>>>(tk_id, tk_w, offsets, poff, tok_list, wt_list,
                                             islot, t_row0, t_e, t_rlim);
    zero_kernel<<<1024, 256, 0, stream>>>((float4*)out, TT * HH / 4);
    gemm1_small<<<dim3(II / 64, TT / 64, EE), 256, 0, stream>>>(x, w1, tok_list, offsets, mid0);
    gemm2_small<<<dim3(HH / 64, TT / 64, EE), 256, 0, stream>>>(mid0, w2, tok_list, wt_list, offsets, out);
  }
}